// Round 8
// baseline (334.481 us; speedup 1.0000x reference)
//
#include <hip/hip_runtime.h>
#include <hip/hip_bf16.h>
#include <cstdint>
#include <cstddef>

#define S_LEN 2048
#define HID   4096
#define HD    128
#define NH    32
#define NKV   8
#define KVW   (NKV * HD)        /* 1024 */
#define QKVN  (HID + 2 * KVW)   /* 6144 */

typedef __bf16 bf16x8_t __attribute__((ext_vector_type(8)));
typedef float  f32x4_t  __attribute__((ext_vector_type(4)));
typedef unsigned short u16x8_t __attribute__((ext_vector_type(8)));

__device__ __forceinline__ unsigned short f2b(float f) {
  unsigned u = __float_as_uint(f);
  u += 0x7FFFu + ((u >> 16) & 1u);
  return (unsigned short)(u >> 16);
}
__device__ __forceinline__ float b2f(unsigned short v) {
  return __uint_as_float(((unsigned)v) << 16);
}
__device__ __forceinline__ void gld_lds16(const void* g, void* l) {
  __builtin_amdgcn_global_load_lds(
      (const __attribute__((address_space(1))) void*)g,
      (__attribute__((address_space(3))) void*)l, 16, 0, 0);
}

// ---------------- fp32 -> bf16 conversion ----------------
__global__ void cvt_kernel(const float* __restrict__ src,
                           unsigned short* __restrict__ dst, int n4) {
  int i = blockIdx.x * blockDim.x + threadIdx.x;
  int stride = gridDim.x * blockDim.x;
  for (; i < n4; i += stride) {
    float4 v = reinterpret_cast<const float4*>(src)[i];
    ushort4 o;
    o.x = f2b(v.x); o.y = f2b(v.y); o.z = f2b(v.z); o.w = f2b(v.w);
    reinterpret_cast<ushort4*>(dst)[i] = o;
  }
}

// ---------------- RoPE (in-place on bf16 Q and K) ----------------
__global__ void rope_kernel(unsigned short* __restrict__ Q,
                            unsigned short* __restrict__ Kb,
                            const int* __restrict__ pos_ids) {
  const int total = S_LEN * (NH + NKV) * 64;
  int idx = blockIdx.x * blockDim.x + threadIdx.x;
  int stride = gridDim.x * blockDim.x;
  for (; idx < total; idx += stride) {
    int s   = idx / ((NH + NKV) * 64);
    int rem = idx % ((NH + NKV) * 64);
    int hp  = rem >> 6;
    int i   = rem & 63;
    unsigned short* ptr; int W, h;
    if (hp < NH) { ptr = Q;  W = HID; h = hp; }
    else         { ptr = Kb; W = KVW; h = hp - NH; }
    float pos = (float)pos_ids[s];
    float ang = pos * __expf(-(float)i * 0.14391156516f); // ln(10000)/64
    float sn, cs;
    sincosf(ang, &sn, &cs);
    size_t base = (size_t)s * W + (size_t)h * HD + i;
    float lo = b2f(ptr[base]);
    float hi = b2f(ptr[base + 64]);
    ptr[base]      = f2b(lo * cs - hi * sn);
    ptr[base + 64] = f2b(hi * cs + lo * sn);
  }
}

// ---------------- 8-phase pipelined GEMM (m201 port): C = A*B^T ----------------
// BK=64, 2 LDS buffers (tile parity), 8 phases per 2 K-tiles.
// Phase = {ds_reads (4..12 b128) | 2 staging DMAs -> barrier -> lgkmcnt(0)
//          -> setprio(1) -> 16 (or 8) MFMA -> setprio(0) -> barrier}.
// vmcnt(VM_N) only at phases 4 & 8 (never 0 in steady state); last iter p4
// drains vmcnt(0) once. Staging plan targets only regions already fully read
// (B consumed in first phase of its tile; A quadrants free 1 phase after last
// read) -- hazard-checked per (phase, region) pair.
// Swizzle: byte-col ^= (row&7)<<4 within 128B rows (both sides: pre-swizzled
// global source + same XOR on ds_read addresses).
// 512 thr = 8 waves (2M x 4N); per-wave out (BM/2) x 64.
// MODE 1: fp32 out. MODE 2: QKV split w/ V transposed.
template <int BM, int MODE>
__global__ __launch_bounds__(512, 2) void gemm8p_kernel(
    const unsigned short* __restrict__ A, const unsigned short* __restrict__ B,
    void* __restrict__ C0, void* __restrict__ C1, void* __restrict__ C2,
    int N, int K) {
  constexpr int BN = 256;
  constexpr int PWM = BM / 2;            // per-wave M rows (128 or 64)
  constexpr int MFR = PWM / 16;          // m-frags per wave (8 or 4)
  constexpr int MPP = MFR / 4;           // m-frags per phase (2 or 1)
  constexpr int ABYTES = BM * 128;       // A region bytes per buffer (BK=64)
  constexpr int TILE_LDS = ABYTES + BN * 128; // 64KB or 48KB
  constexpr int A_UNITS = ABYTES / 8192; // 4 or 2 (8KB units)
  constexpr int TUNITS = A_UNITS + 4;    // 8 or 6
  constexpr int VM_N = TUNITS - 2;       // 6 or 4
  __shared__ char ldsB[2 * TILE_LDS];

  const int tid  = threadIdx.x;
  const int lane = tid & 63;
  const int wid  = tid >> 6;
  const int wm = wid >> 2, wn = wid & 3;
  const int lr = lane & 15, g = lane >> 4;

  // XCD-aware block swizzle (grid % 8 == 0 for both call sites)
  const int gx = gridDim.x;
  const int nwg = gx * gridDim.y;
  const int lin = blockIdx.y * gx + blockIdx.x;
  const int swz = (lin & 7) * (nwg >> 3) + (lin >> 3);
  const int bm = (swz / gx) * BM;
  const int bn = (swz % gx) * BN;

  const int nk = K >> 6;                 // K64 tiles
  const int ni = nk >> 1;                // iterations (2 tiles each)
  const int xr = (lr & 7) << 4;          // read-side swizzle XOR

  // stage unit u (8KB = 64 rows x 128B) of K-tile t into buf (t&1)
  auto stage_u = [&](int t, int u) {
    if (t >= nk) return;
    const int riu = tid >> 3;                 // row in unit 0..63
    const int cbs = ((tid & 7) << 4) ^ ((riu & 7) << 4);  // swizzled src col
    const char* src;
    if (u < A_UNITS)
      src = (const char*)A + ((size_t)(bm + u * 64 + riu) * K + t * 64) * 2 + cbs;
    else
      src = (const char*)B + ((size_t)(bn + (u - A_UNITS) * 64 + riu) * K + t * 64) * 2 + cbs;
    gld_lds16(src, ldsB + (t & 1) * TILE_LDS + u * 8192 + tid * 16);
  };

  auto rdA = [&](const char* bb, int m, int k) {
    const int row = wm * PWM + m * 16 + lr;
    return *(const bf16x8_t*)(bb + row * 128 + ((k * 64 + g * 16) ^ xr));
  };
  auto rdB = [&](const char* bb, int n, int k) {
    const int row = wn * 64 + n * 16 + lr;
    return *(const bf16x8_t*)(bb + ABYTES + row * 128 + ((k * 64 + g * 16) ^ xr));
  };

  // prologue: stage tiles 0,1 fully; drain once; barrier
  for (int t = 0; t < 2; ++t)
    for (int u = 0; u < TUNITS; ++u) stage_u(t, u);
  asm volatile("s_waitcnt vmcnt(0)" ::: "memory");
  __builtin_amdgcn_sched_barrier(0);
  __builtin_amdgcn_s_barrier();

  f32x4_t acc[MFR][4];
#pragma unroll
  for (int m = 0; m < MFR; ++m)
#pragma unroll
    for (int n = 0; n < 4; ++n) acc[m][n] = f32x4_t{0.f, 0.f, 0.f, 0.f};

  bf16x8_t bfr[4][2], af[MPP][2];

#define MFMA_BLOCK(MB)                                                        \
  __builtin_amdgcn_s_setprio(1);                                              \
  _Pragma("unroll") for (int m = 0; m < MPP; ++m)                             \
    _Pragma("unroll") for (int n = 0; n < 4; ++n)                             \
      _Pragma("unroll") for (int k = 0; k < 2; ++k)                           \
        acc[(MB) + m][n] = __builtin_amdgcn_mfma_f32_16x16x32_bf16(           \
            af[m][k], bfr[n][k], acc[(MB) + m][n], 0, 0, 0);                  \
  __builtin_amdgcn_s_setprio(0);

#define GATE()                                                                \
  __builtin_amdgcn_s_barrier();                                               \
  asm volatile("s_waitcnt lgkmcnt(0)" ::: "memory");                          \
  __builtin_amdgcn_sched_barrier(0);

  for (int i = 0; i < ni; ++i) {
    const char* baseE = ldsB;              // tile 2i   (even -> buf0)
    const char* baseO = ldsB + TILE_LDS;   // tile 2i+1 (odd  -> buf1)
    const int tO = 2 * i + 1, tE2 = 2 * i + 2, tO2 = 2 * i + 3;
    const bool last = (i == ni - 1);

    // ---- phase 1: B(E) all + A(E) frags [0,MPP) ----
#pragma unroll
    for (int n = 0; n < 4; ++n)
#pragma unroll
      for (int k = 0; k < 2; ++k) bfr[n][k] = rdB(baseE, n, k);
#pragma unroll
    for (int m = 0; m < MPP; ++m)
#pragma unroll
      for (int k = 0; k < 2; ++k) af[m][k] = rdA(baseE, m, k);
    if (i > 0) {
      if constexpr (BM == 256) { stage_u(tO, 1); stage_u(tO, 3); }
      else                     { stage_u(tO, 0); stage_u(tO, 1); }
    }
    GATE(); MFMA_BLOCK(0);
    __builtin_amdgcn_s_barrier();

    // ---- phase 2 ----
#pragma unroll
    for (int m = 0; m < MPP; ++m)
#pragma unroll
      for (int k = 0; k < 2; ++k) af[m][k] = rdA(baseE, MPP + m, k);
    stage_u(tE2, A_UNITS + 0); stage_u(tE2, A_UNITS + 1);
    GATE(); MFMA_BLOCK(MPP);
    __builtin_amdgcn_s_barrier();

    // ---- phase 3 ----
#pragma unroll
    for (int m = 0; m < MPP; ++m)
#pragma unroll
      for (int k = 0; k < 2; ++k) af[m][k] = rdA(baseE, 2 * MPP + m, k);
    stage_u(tE2, A_UNITS + 2); stage_u(tE2, A_UNITS + 3);
    GATE(); MFMA_BLOCK(2 * MPP);
    __builtin_amdgcn_s_barrier();

    // ---- phase 4 (+ vmcnt before barrier) ----
#pragma unroll
    for (int m = 0; m < MPP; ++m)
#pragma unroll
      for (int k = 0; k < 2; ++k) af[m][k] = rdA(baseE, 3 * MPP + m, k);
    if constexpr (BM == 256) { stage_u(tE2, 0); stage_u(tE2, 2); }
    GATE(); MFMA_BLOCK(3 * MPP);
    if (last) { asm volatile("s_waitcnt vmcnt(0)" ::: "memory"); }
    else      { asm volatile("s_waitcnt vmcnt(%0)" :: "n"(VM_N) : "memory"); }
    __builtin_amdgcn_sched_barrier(0);
    __builtin_amdgcn_s_barrier();

    // ---- phase 5: B(O) all + A(O) frags [0,MPP) ----
#pragma unroll
    for (int n = 0; n < 4; ++n)
#pragma unroll
      for (int k = 0; k < 2; ++k) bfr[n][k] = rdB(baseO, n, k);
#pragma unroll
    for (int m = 0; m < MPP; ++m)
#pragma unroll
      for (int k = 0; k < 2; ++k) af[m][k] = rdA(baseO, m, k);
    if constexpr (BM == 256) { stage_u(tE2, 1); stage_u(tE2, 3); }
    else                     { stage_u(tE2, 0); stage_u(tE2, 1); }
    GATE(); MFMA_BLOCK(0);
    __builtin_amdgcn_s_barrier();

    // ---- phase 6 ----
#pragma unroll
    for (int m = 0; m < MPP; ++m)
#pragma unroll
      for (int k = 0; k < 2; ++k) af[m][k] = rdA(baseO, MPP + m, k);
    stage_u(tO2, A_UNITS + 0); stage_u(tO2, A_UNITS + 1);
    GATE(); MFMA_BLOCK(MPP);
    __builtin_amdgcn_s_barrier();

    // ---- phase 7 ----
#pragma unroll
    for (int m = 0; m < MPP; ++m)
#pragma unroll
      for (int k = 0; k < 2; ++k) af[m][k] = rdA(baseO, 2 * MPP + m, k);
    stage_u(tO2, A_UNITS + 2); stage_u(tO2, A_UNITS + 3);
    GATE(); MFMA_BLOCK(2 * MPP);
    __builtin_amdgcn_s_barrier();

    // ---- phase 8 (+ vmcnt before barrier, skip on last) ----
#pragma unroll
    for (int m = 0; m < MPP; ++m)
#pragma unroll
      for (int k = 0; k < 2; ++k) af[m][k] = rdA(baseO, 3 * MPP + m, k);
    if constexpr (BM == 256) { stage_u(tO2, 0); stage_u(tO2, 2); }
    GATE(); MFMA_BLOCK(3 * MPP);
    if (!last) { asm volatile("s_waitcnt vmcnt(%0)" :: "n"(VM_N) : "memory"); }
    __builtin_amdgcn_sched_barrier(0);
    __builtin_amdgcn_s_barrier();
  }
#undef MFMA_BLOCK
#undef GATE

  // ---- epilogue ----
#pragma unroll
  for (int mf = 0; mf < MFR; ++mf) {
    const int row0 = bm + wm * PWM + mf * 16 + g * 4;
#pragma unroll
    for (int nf = 0; nf < 4; ++nf) {
      const int col = bn + wn * 64 + nf * 16 + lr;
      if constexpr (MODE == 1) {
#pragma unroll
        for (int r = 0; r < 4; ++r)
          ((float*)C0)[(size_t)(row0 + r) * N + col] = acc[mf][nf][r];
      } else {
        if (col < HID) {
#pragma unroll
          for (int r = 0; r < 4; ++r)
            ((unsigned short*)C0)[(size_t)(row0 + r) * HID + col] = f2b(acc[mf][nf][r]);
        } else if (col < HID + KVW) {
#pragma unroll
          for (int r = 0; r < 4; ++r)
            ((unsigned short*)C1)[(size_t)(row0 + r) * KVW + (col - HID)] = f2b(acc[mf][nf][r]);
        } else {
          const int c2 = col - HID - KVW;
          ushort4 w;
          w.x = f2b(acc[mf][nf][0]); w.y = f2b(acc[mf][nf][1]);
          w.z = f2b(acc[mf][nf][2]); w.w = f2b(acc[mf][nf][3]);
          *(ushort4*)(void*)&((unsigned short*)C2)[(size_t)c2 * S_LEN + row0] = w;
        }
      }
    }
  }
}

// ---------------- flash attention v3 (causal, GQA 4:1) ----------------
__global__ __launch_bounds__(256) void attn_kernel(
    const unsigned short* __restrict__ Q, const unsigned short* __restrict__ K,
    const unsigned short* __restrict__ VtG, unsigned short* __restrict__ O) {
  __shared__ unsigned short Kl[64][136];
  __shared__ unsigned short Vt[128][72];
  __shared__ unsigned short Pl[4][16][72];

  const int tid  = threadIdx.x;
  const int lane = tid & 63;
  const int wave = tid >> 6;
  const int h    = blockIdx.y;
  const int kvh  = h >> 2;
  const int pair = blockIdx.x;             // [0,16)
  const int lr   = lane & 15;
  const int g    = lane >> 4;
  const int lk8  = g * 8;
  const float scale = 0.08838834764831845f;  // 1/sqrt(128)
  const unsigned short* Vbase = VtG + (size_t)kvh * HD * S_LEN;

  const int ksr = tid >> 4, ksc = (tid & 15) * 8;
  const int vsr = tid >> 3, vsc = (tid & 7) * 8;

  for (int pass = 0; pass < 2; ++pass) {
    const int qb = pass == 0 ? (31 - pair) : pair;
    const int q0 = qb * 64;
    const int qrow = q0 + wave * 16;
    const int nkv = qb + 1;

    bf16x8_t qf[4];
    {
      const unsigned short* qp = Q + (size_t)(qrow + lr) * HID + (size_t)h * HD;
#pragma unroll
      for (int c = 0; c < 4; ++c)
        qf[c] = *(const bf16x8_t*)(const void*)(qp + c * 32 + lk8);
    }
    f32x4_t oacc[8];
#pragma unroll
    for (int c = 0; c < 8; ++c) oacc[c] = f32x4_t{0.f, 0.f, 0.f, 0.f};
    float m_run = -3e38f, l_run = 0.f;

    u16x8_t kr[4], vr[4];
#pragma unroll
    for (int i = 0; i < 4; ++i)
      kr[i] = *(const u16x8_t*)(const void*)(K + (size_t)(ksr + i * 16) * KVW +
                                             (size_t)kvh * HD + ksc);
#pragma unroll
    for (int i = 0; i < 4; ++i)
      vr[i] = *(const u16x8_t*)(const void*)(Vbase + (size_t)(vsr + i * 32) * S_LEN + vsc);

    for (int it = 0; it < nkv; ++it) {
      const int kv0 = it * 64;
      __builtin_amdgcn_s_barrier();
#pragma unroll
      for (int i = 0; i < 4; ++i)
        *(u16x8_t*)(void*)&Kl[ksr + i * 16][ksc] = kr[i];
#pragma unroll
      for (int i = 0; i < 4; ++i)
        *(u16x8_t*)(void*)&Vt[vsr + i * 32][vsc] = vr[i];
      if (it + 1 < nkv) {
        const int kn = kv0 + 64;
#pragma unroll
        for (int i = 0; i < 4; ++i)
          kr[i] = *(const u16x8_t*)(const void*)(K + (size_t)(kn + ksr + i * 16) * KVW +
                                                 (size_t)kvh * HD + ksc);
#pragma unroll
        for (int i = 0; i < 4; ++i)
          vr[i] = *(const u16x8_t*)(const void*)(Vbase + (size_t)(vsr + i * 32) * S_LEN +
                                                 kn + vsc);
      }
      asm volatile("s_waitcnt lgkmcnt(0)" ::: "memory");
      __builtin_amdgcn_sched_barrier(0);
      __builtin_amdgcn_s_barrier();

      f32x4_t sacc[4];
#pragma unroll
      for (int n = 0; n < 4; ++n) sacc[n] = f32x4_t{0.f, 0.f, 0.f, 0.f};
#pragma unroll
      for (int c = 0; c < 4; ++c) {
        bf16x8_t qc = qf[c];
#pragma unroll
        for (int n = 0; n < 4; ++n) {
          bf16x8_t kf = *(const bf16x8_t*)(const void*)&Kl[n * 16 + lr][c * 32 + lk8];
          sacc[n] = __builtin_amdgcn_mfma_f32_16x16x32_bf16(kf, qc, sacc[n], 0, 0, 0);
        }
      }

      const int qg = qrow + lr;
      const bool diag = (it == nkv - 1);
      float p[16];
      float mloc = -3e38f;
#pragma unroll
      for (int n = 0; n < 4; ++n)
#pragma unroll
        for (int r = 0; r < 4; ++r) {
          float x = sacc[n][r] * scale;
          if (diag) {
            int kg = kv0 + n * 16 + g * 4 + r;
            if (kg > qg) x = -3e38f;
          }
          p[n * 4 + r] = x;
          mloc = fmaxf(mloc, x);
        }
      mloc = fmaxf(mloc, __shfl_xor(mloc, 16));
      mloc = fmaxf(mloc, __shfl_xor(mloc, 32));

      if (__any(mloc > m_run + 8.f)) {
        float m_new = fmaxf(m_run, mloc);
        float alpha = __expf(m_run - m_new);
        float a4[4];
#pragma unroll
        for (int r = 0; r < 4; ++r) a4[r] = __shfl(alpha, g * 4 + r);
#pragma unroll
        for (int c = 0; c < 8; ++c)
#pragma unroll
          for (int r = 0; r < 4; ++r) oacc[c][r] *= a4[r];
        l_run *= alpha;
        m_run = m_new;
      }

      float ssum = 0.f;
#pragma unroll
      for (int i = 0; i < 16; ++i) {
        float e = __expf(p[i] - m_run);
        p[i] = e;
        ssum += e;
      }
      ssum += __shfl_xor(ssum, 16);
      ssum += __shfl_xor(ssum, 32);
      l_run += ssum;

#pragma unroll
      for (int n = 0; n < 4; ++n) {
        ushort4 w;
        w.x = f2b(p[n * 4 + 0]); w.y = f2b(p[n * 4 + 1]);
        w.z = f2b(p[n * 4 + 2]); w.w = f2b(p[n * 4 + 3]);
        *(ushort4*)(void*)&Pl[wave][lr][n * 16 + g * 4] = w;
      }

#pragma unroll
      for (int half = 0; half < 2; ++half) {
        bf16x8_t pf = *(const bf16x8_t*)(const void*)&Pl[wave][lr][half * 32 + lk8];
#pragma unroll
        for (int c = 0; c < 8; ++c) {
          bf16x8_t vf = *(const bf16x8_t*)(const void*)&Vt[c * 16 + lr][half * 32 + lk8];
          oacc[c] = __builtin_amdgcn_mfma_f32_16x16x32_bf16(pf, vf, oacc[c], 0, 0, 0);
        }
      }
    }

    float linv[4];
#pragma unroll
    for (int r = 0; r < 4; ++r) linv[r] = 1.f / __shfl(l_run, g * 4 + r);
#pragma unroll
    for (int r = 0; r < 4; ++r) {
      int row = qrow + g * 4 + r;
#pragma unroll
      for (int c = 0; c < 8; ++c)
        O[(size_t)row * HID + (size_t)h * HD + c * 16 + lr] = f2b(oacc[c][r] * linv[r]);
    }
  }
}

// ---------------- host launch ----------------
extern "C" void kernel_launch(void* const* d_in, const int* in_sizes, int n_in,
                              void* d_out, int out_size, void* d_ws, size_t ws_size,
                              hipStream_t stream) {
  (void)in_sizes; (void)n_in; (void)out_size; (void)ws_size;
  const float* X  = (const float*)d_in[0];
  const float* Wq = (const float*)d_in[1];
  const float* Wk = (const float*)d_in[2];
  const float* Wv = (const float*)d_in[3];
  const float* Wo = (const float*)d_in[4];
  const int*  pos = (const int*)d_in[5];
  float* out = (float*)d_out;

  unsigned short* Xb  = (unsigned short*)d_ws;
  unsigned short* Wqb = Xb  + (size_t)S_LEN * HID;
  unsigned short* Wkb = Wqb + (size_t)HID * HID;    // contiguous with Wqb
  unsigned short* Wvb = Wkb + (size_t)KVW * HID;    // contiguous -> [6144 x 4096] B
  unsigned short* Wob = Wvb + (size_t)KVW * HID;
  unsigned short* Qb  = Wob + (size_t)HID * HID;
  unsigned short* Kb  = Qb  + (size_t)S_LEN * HID;
  unsigned short* VtB = Kb  + (size_t)S_LEN * KVW;  // V^T: [KVW][S_LEN]
  unsigned short* AOb = VtB + (size_t)S_LEN * KVW;

  auto cvt = [&](const float* s, unsigned short* d, size_t n) {
    int n4 = (int)(n / 4);
    int grid = (n4 + 255) / 256;
    if (grid > 4096) grid = 4096;
    cvt_kernel<<<grid, 256, 0, stream>>>(s, d, n4);
  };
  cvt(X,  Xb,  (size_t)S_LEN * HID);
  cvt(Wq, Wqb, (size_t)HID * HID);
  cvt(Wk, Wkb, (size_t)KVW * HID);
  cvt(Wv, Wvb, (size_t)KVW * HID);
  cvt(Wo, Wob, (size_t)HID * HID);

  // QKV projection: 256x256 tiles, grid 24x8 = 192 blocks
  gemm8p_kernel<256, 2><<<dim3(QKVN / 256, S_LEN / 256), 512, 0, stream>>>(
      Xb, Wqb, Qb, Kb, VtB, QKVN, HID);

  rope_kernel<<<2048, 256, 0, stream>>>(Qb, Kb, pos);

  // folded-balance attention: 16 pair-blocks x 32 heads
  attn_kernel<<<dim3(16, NH), 256, 0, stream>>>(Qb, Kb, VtB, AOb);

  // output projection: 128x256 tiles, grid 16x16 = 256 blocks -> fp32
  gemm8p_kernel<128, 1><<<dim3(HID / 256, S_LEN / 128), 512, 0, stream>>>(
      AOb, Wob, out, nullptr, nullptr, HID, HID);
}

// Round 9
// 308.122 us; speedup vs baseline: 1.0855x; 1.0855x over previous
//
#include <hip/hip_runtime.h>
#include <hip/hip_bf16.h>
#include <cstdint>
#include <cstddef>

#define S_LEN 2048
#define HID   4096
#define HD    128
#define NH    32
#define NKV   8
#define KVW   (NKV * HD)        /* 1024 */
#define QKVN  (HID + 2 * KVW)   /* 6144 */

typedef __bf16 bf16x8_t __attribute__((ext_vector_type(8)));
typedef float  f32x4_t  __attribute__((ext_vector_type(4)));
typedef unsigned short u16x8_t __attribute__((ext_vector_type(8)));

__device__ __forceinline__ unsigned short f2b(float f) {
  unsigned u = __float_as_uint(f);
  u += 0x7FFFu + ((u >> 16) & 1u);
  return (unsigned short)(u >> 16);
}
__device__ __forceinline__ float b2f(unsigned short v) {
  return __uint_as_float(((unsigned)v) << 16);
}
__device__ __forceinline__ void gld_lds16(const void* g, void* l) {
  __builtin_amdgcn_global_load_lds(
      (const __attribute__((address_space(1))) void*)g,
      (__attribute__((address_space(3))) void*)l, 16, 0, 0);
}

// ---------------- fp32 -> bf16 conversion ----------------
__global__ void cvt_kernel(const float* __restrict__ src,
                           unsigned short* __restrict__ dst, int n4) {
  int i = blockIdx.x * blockDim.x + threadIdx.x;
  int stride = gridDim.x * blockDim.x;
  for (; i < n4; i += stride) {
    float4 v = reinterpret_cast<const float4*>(src)[i];
    ushort4 o;
    o.x = f2b(v.x); o.y = f2b(v.y); o.z = f2b(v.z); o.w = f2b(v.w);
    reinterpret_cast<ushort4*>(dst)[i] = o;
  }
}

// ---------------- RoPE (in-place on bf16 Q and K) ----------------
__global__ void rope_kernel(unsigned short* __restrict__ Q,
                            unsigned short* __restrict__ Kb,
                            const int* __restrict__ pos_ids) {
  const int total = S_LEN * (NH + NKV) * 64;
  int idx = blockIdx.x * blockDim.x + threadIdx.x;
  int stride = gridDim.x * blockDim.x;
  for (; idx < total; idx += stride) {
    int s   = idx / ((NH + NKV) * 64);
    int rem = idx % ((NH + NKV) * 64);
    int hp  = rem >> 6;
    int i   = rem & 63;
    unsigned short* ptr; int W, h;
    if (hp < NH) { ptr = Q;  W = HID; h = hp; }
    else         { ptr = Kb; W = KVW; h = hp - NH; }
    float pos = (float)pos_ids[s];
    float ang = pos * __expf(-(float)i * 0.14391156516f); // ln(10000)/64
    float sn, cs;
    sincosf(ang, &sn, &cs);
    size_t base = (size_t)s * W + (size_t)h * HD + i;
    float lo = b2f(ptr[base]);
    float hi = b2f(ptr[base + 64]);
    ptr[base]      = f2b(lo * cs - hi * sn);
    ptr[base + 64] = f2b(hi * cs + lo * sn);
  }
}

// ---------------- 8-phase pipelined GEMM: C = A(Mx K) * B(NxK)^T ----------------
// BM=256 fixed. BK=64, 2 LDS buffers (tile parity), 8 phases / 2 K-tiles.
// Per phase: {ds_reads | <=2 staging DMAs -> barrier -> lgkmcnt(0) ->
//             setprio(1) -> 2m x NFR x 2k MFMA -> setprio(0) -> barrier}.
// Units: 8KB = 64 rows x 128B. A units u0..u3, B units u4..u3+BU (BU=BN/64).
// Consumption: B all in p1; u0,u2 (A m0-3) free after p2; u1,u3 free after p4.
// Stage map (tile parity mirrored p5-8): p1:{tO u1,u3 (i>0)} p2:{tE2 u4,u5}
//   p3:{BU3? u6,u0 : u0,u2} p4:{BU3? u2 : -} p5:{tE2 u1,u3} p6-8 mirror tO2.
// vmcnt(VM_N = BU+2) at p4/p8 only (never 0 in steady state; drain at last p4).
// Every (phase,region) WAR pair fenced by the previous phase-end barrier
// (reads are lgkmcnt(0)-drained before each phase's MFMA, hence before that
// barrier). Swizzle: byte ^= (row&7)<<4, both sides. Natural block order
// (no XCD swizzle - r8 showed it doubles L2 fill here). Grid = (N/BN, M/256).
// MODE 1: fp32 out. MODE 2: QKV split w/ V transposed.
template <int BN, int MODE>
__global__ __launch_bounds__(512, 2) void gemm8p_kernel(
    const unsigned short* __restrict__ A, const unsigned short* __restrict__ B,
    void* __restrict__ C0, void* __restrict__ C1, void* __restrict__ C2,
    int N, int K) {
  constexpr int NFR = BN / 64;           // n-frags per wave (3 or 2) == B units
  constexpr int ABYTES = 256 * 128;      // 32 KB
  constexpr int TILE_LDS = ABYTES + BN * 128;
  constexpr int VM_N = NFR + 2;          // 5 or 4
  __shared__ char ldsB[2 * TILE_LDS];

  const int tid  = threadIdx.x;
  const int lane = tid & 63;
  const int wid  = tid >> 6;
  const int wm = wid >> 2, wn = wid & 3;
  const int lr = lane & 15, g = lane >> 4;
  const int bm = blockIdx.y * 256;
  const int bn = blockIdx.x * BN;
  const int nk = K >> 6;
  const int ni = nk >> 1;
  const int xr = (lr & 7) << 4;

  // stage unit u of K-tile t into buf (t&1). u<4: A rows u*64..; else B rows.
  auto stage_u = [&](int t, int u) {
    if (t >= nk) return;
    const int riu = tid >> 3;
    const int cbs = ((tid & 7) << 4) ^ ((riu & 7) << 4);
    const char* src;
    if (u < 4)
      src = (const char*)A + ((size_t)(bm + u * 64 + riu) * K + t * 64) * 2 + cbs;
    else
      src = (const char*)B + ((size_t)(bn + (u - 4) * 64 + riu) * K + t * 64) * 2 + cbs;
    gld_lds16(src, ldsB + (t & 1) * TILE_LDS + u * 8192 + tid * 16);
  };

  auto rdA = [&](const char* bb, int m, int k) {
    const int row = wm * 128 + m * 16 + lr;
    return *(const bf16x8_t*)(bb + row * 128 + ((k * 64 + g * 16) ^ xr));
  };
  auto rdB = [&](const char* bb, int n, int k) {
    const int row = wn * (BN / 4) + n * 16 + lr;
    return *(const bf16x8_t*)(bb + ABYTES + row * 128 + ((k * 64 + g * 16) ^ xr));
  };

  // prologue: stage tiles 0,1 fully; drain; barrier
  for (int t = 0; t < 2; ++t)
    for (int u = 0; u < 4 + NFR; ++u) stage_u(t, u);
  asm volatile("s_waitcnt vmcnt(0)" ::: "memory");
  __builtin_amdgcn_sched_barrier(0);
  __builtin_amdgcn_s_barrier();

  f32x4_t acc[8][NFR];
#pragma unroll
  for (int m = 0; m < 8; ++m)
#pragma unroll
    for (int n = 0; n < NFR; ++n) acc[m][n] = f32x4_t{0.f, 0.f, 0.f, 0.f};

  bf16x8_t bfr[NFR][2], af[2][2];

#define MFMA_BLOCK(MB)                                                        \
  __builtin_amdgcn_s_setprio(1);                                              \
  _Pragma("unroll") for (int m = 0; m < 2; ++m)                               \
    _Pragma("unroll") for (int n = 0; n < NFR; ++n)                           \
      _Pragma("unroll") for (int k = 0; k < 2; ++k)                           \
        acc[(MB) + m][n] = __builtin_amdgcn_mfma_f32_16x16x32_bf16(           \
            af[m][k], bfr[n][k], acc[(MB) + m][n], 0, 0, 0);                  \
  __builtin_amdgcn_s_setprio(0);

#define GATE()                                                                \
  __builtin_amdgcn_s_barrier();                                               \
  asm volatile("s_waitcnt lgkmcnt(0)" ::: "memory");                          \
  __builtin_amdgcn_sched_barrier(0);

#define RD_A2(bb, m0)                                                         \
  _Pragma("unroll") for (int m = 0; m < 2; ++m)                               \
    _Pragma("unroll") for (int k = 0; k < 2; ++k)                             \
      af[m][k] = rdA(bb, (m0) + m, k);

  for (int i = 0; i < ni; ++i) {
    const char* baseE = ldsB;
    const char* baseO = ldsB + TILE_LDS;
    const int tO = 2 * i + 1, tE2 = 2 * i + 2, tO2 = 2 * i + 3;
    const bool last = (i == ni - 1);

    // ---- p1: B(E) all + A(E) m0,1 ----
#pragma unroll
    for (int n = 0; n < NFR; ++n)
#pragma unroll
      for (int k = 0; k < 2; ++k) bfr[n][k] = rdB(baseE, n, k);
    RD_A2(baseE, 0);
    if (i > 0) { stage_u(tO, 1); stage_u(tO, 3); }
    GATE(); MFMA_BLOCK(0);
    __builtin_amdgcn_s_barrier();

    // ---- p2: A(E) m2,3 ----
    RD_A2(baseE, 2);
    stage_u(tE2, 4); stage_u(tE2, 5);
    GATE(); MFMA_BLOCK(2);
    __builtin_amdgcn_s_barrier();

    // ---- p3: A(E) m4,5 ----
    RD_A2(baseE, 4);
    if constexpr (NFR == 3) { stage_u(tE2, 6); stage_u(tE2, 0); }
    else                    { stage_u(tE2, 0); stage_u(tE2, 2); }
    GATE(); MFMA_BLOCK(4);
    __builtin_amdgcn_s_barrier();

    // ---- p4: A(E) m6,7 (+ vmcnt before barrier) ----
    RD_A2(baseE, 6);
    if constexpr (NFR == 3) { stage_u(tE2, 2); }
    GATE(); MFMA_BLOCK(6);
    if (last) { asm volatile("s_waitcnt vmcnt(0)" ::: "memory"); }
    else      { asm volatile("s_waitcnt vmcnt(%0)" :: "n"(VM_N) : "memory"); }
    __builtin_amdgcn_sched_barrier(0);
    __builtin_amdgcn_s_barrier();

    // ---- p5: B(O) all + A(O) m0,1 ----
#pragma unroll
    for (int n = 0; n < NFR; ++n)
#pragma unroll
      for (int k = 0; k < 2; ++k) bfr[n][k] = rdB(baseO, n, k);
    RD_A2(baseO, 0);
    stage_u(tE2, 1); stage_u(tE2, 3);
    GATE(); MFMA_BLOCK(0);
    __builtin_amdgcn_s_barrier();

    // ---- p6: A(O) m2,3 ----
    RD_A2(baseO, 2);
    stage_u(tO2, 4); stage_u(tO2, 5);
    GATE(); MFMA_BLOCK(2);
    __builtin_amdgcn_s_barrier();

    // ---- p7: A(O) m4,5 ----
    RD_A2(baseO, 4);
    if constexpr (NFR == 3) { stage_u(tO2, 6); stage_u(tO2, 0); }
    else                    { stage_u(tO2, 0); stage_u(tO2, 2); }
    GATE(); MFMA_BLOCK(4);
    __builtin_amdgcn_s_barrier();

    // ---- p8: A(O) m6,7 (+ vmcnt, skip on last) ----
    RD_A2(baseO, 6);
    if constexpr (NFR == 3) { stage_u(tO2, 2); }
    GATE(); MFMA_BLOCK(6);
    if (!last) { asm volatile("s_waitcnt vmcnt(%0)" :: "n"(VM_N) : "memory"); }
    __builtin_amdgcn_sched_barrier(0);
    __builtin_amdgcn_s_barrier();
  }
#undef MFMA_BLOCK
#undef GATE
#undef RD_A2

  // ---- epilogue ----
#pragma unroll
  for (int mf = 0; mf < 8; ++mf) {
    const int row0 = bm + wm * 128 + mf * 16 + g * 4;
#pragma unroll
    for (int nf = 0; nf < NFR; ++nf) {
      const int col = bn + wn * (BN / 4) + nf * 16 + lr;
      if constexpr (MODE == 1) {
#pragma unroll
        for (int r = 0; r < 4; ++r)
          ((float*)C0)[(size_t)(row0 + r) * N + col] = acc[mf][nf][r];
      } else {
        if (col < HID) {
#pragma unroll
          for (int r = 0; r < 4; ++r)
            ((unsigned short*)C0)[(size_t)(row0 + r) * HID + col] = f2b(acc[mf][nf][r]);
        } else if (col < HID + KVW) {
#pragma unroll
          for (int r = 0; r < 4; ++r)
            ((unsigned short*)C1)[(size_t)(row0 + r) * KVW + (col - HID)] = f2b(acc[mf][nf][r]);
        } else {
          const int c2 = col - HID - KVW;
          ushort4 w;
          w.x = f2b(acc[mf][nf][0]); w.y = f2b(acc[mf][nf][1]);
          w.z = f2b(acc[mf][nf][2]); w.w = f2b(acc[mf][nf][3]);
          *(ushort4*)(void*)&((unsigned short*)C2)[(size_t)c2 * S_LEN + row0] = w;
        }
      }
    }
  }
}

// ---------------- flash attention v3 (causal, GQA 4:1) ----------------
__global__ __launch_bounds__(256) void attn_kernel(
    const unsigned short* __restrict__ Q, const unsigned short* __restrict__ K,
    const unsigned short* __restrict__ VtG, unsigned short* __restrict__ O) {
  __shared__ unsigned short Kl[64][136];
  __shared__ unsigned short Vt[128][72];
  __shared__ unsigned short Pl[4][16][72];

  const int tid  = threadIdx.x;
  const int lane = tid & 63;
  const int wave = tid >> 6;
  const int h    = blockIdx.y;
  const int kvh  = h >> 2;
  const int pair = blockIdx.x;             // [0,16)
  const int lr   = lane & 15;
  const int g    = lane >> 4;
  const int lk8  = g * 8;
  const float scale = 0.08838834764831845f;  // 1/sqrt(128)
  const unsigned short* Vbase = VtG + (size_t)kvh * HD * S_LEN;

  const int ksr = tid >> 4, ksc = (tid & 15) * 8;
  const int vsr = tid >> 3, vsc = (tid & 7) * 8;

  for (int pass = 0; pass < 2; ++pass) {
    const int qb = pass == 0 ? (31 - pair) : pair;
    const int q0 = qb * 64;
    const int qrow = q0 + wave * 16;
    const int nkv = qb + 1;

    bf16x8_t qf[4];
    {
      const unsigned short* qp = Q + (size_t)(qrow + lr) * HID + (size_t)h * HD;
#pragma unroll
      for (int c = 0; c < 4; ++c)
        qf[c] = *(const bf16x8_t*)(const void*)(qp + c * 32 + lk8);
    }
    f32x4_t oacc[8];
#pragma unroll
    for (int c = 0; c < 8; ++c) oacc[c] = f32x4_t{0.f, 0.f, 0.f, 0.f};
    float m_run = -3e38f, l_run = 0.f;

    u16x8_t kr[4], vr[4];
#pragma unroll
    for (int i = 0; i < 4; ++i)
      kr[i] = *(const u16x8_t*)(const void*)(K + (size_t)(ksr + i * 16) * KVW +
                                             (size_t)kvh * HD + ksc);
#pragma unroll
    for (int i = 0; i < 4; ++i)
      vr[i] = *(const u16x8_t*)(const void*)(Vbase + (size_t)(vsr + i * 32) * S_LEN + vsc);

    for (int it = 0; it < nkv; ++it) {
      const int kv0 = it * 64;
      __builtin_amdgcn_s_barrier();
#pragma unroll
      for (int i = 0; i < 4; ++i)
        *(u16x8_t*)(void*)&Kl[ksr + i * 16][ksc] = kr[i];
#pragma unroll
      for (int i = 0; i < 4; ++i)
        *(u16x8_t*)(void*)&Vt[vsr + i * 32][vsc] = vr[i];
      if (it + 1 < nkv) {
        const int kn = kv0 + 64;
#pragma unroll
        for (int i = 0; i < 4; ++i)
          kr[i] = *(const u16x8_t*)(const void*)(K + (size_t)(kn + ksr + i * 16) * KVW +
                                                 (size_t)kvh * HD + ksc);
#pragma unroll
        for (int i = 0; i < 4; ++i)
          vr[i] = *(const u16x8_t*)(const void*)(Vbase + (size_t)(vsr + i * 32) * S_LEN +
                                                 kn + vsc);
      }
      asm volatile("s_waitcnt lgkmcnt(0)" ::: "memory");
      __builtin_amdgcn_sched_barrier(0);
      __builtin_amdgcn_s_barrier();

      f32x4_t sacc[4];
#pragma unroll
      for (int n = 0; n < 4; ++n) sacc[n] = f32x4_t{0.f, 0.f, 0.f, 0.f};
#pragma unroll
      for (int c = 0; c < 4; ++c) {
        bf16x8_t qc = qf[c];
#pragma unroll
        for (int n = 0; n < 4; ++n) {
          bf16x8_t kf = *(const bf16x8_t*)(const void*)&Kl[n * 16 + lr][c * 32 + lk8];
          sacc[n] = __builtin_amdgcn_mfma_f32_16x16x32_bf16(kf, qc, sacc[n], 0, 0, 0);
        }
      }

      const int qg = qrow + lr;
      const bool diag = (it == nkv - 1);
      float p[16];
      float mloc = -3e38f;
#pragma unroll
      for (int n = 0; n < 4; ++n)
#pragma unroll
        for (int r = 0; r < 4; ++r) {
          float x = sacc[n][r] * scale;
          if (diag) {
            int kg = kv0 + n * 16 + g * 4 + r;
            if (kg > qg) x = -3e38f;
          }
          p[n * 4 + r] = x;
          mloc = fmaxf(mloc, x);
        }
      mloc = fmaxf(mloc, __shfl_xor(mloc, 16));
      mloc = fmaxf(mloc, __shfl_xor(mloc, 32));

      if (__any(mloc > m_run + 8.f)) {
        float m_new = fmaxf(m_run, mloc);
        float alpha = __expf(m_run - m_new);
        float a4[4];
#pragma unroll
        for (int r = 0; r < 4; ++r) a4[r] = __shfl(alpha, g * 4 + r);
#pragma unroll
        for (int c = 0; c < 8; ++c)
#pragma unroll
          for (int r = 0; r < 4; ++r) oacc[c][r] *= a4[r];
        l_run *= alpha;
        m_run = m_new;
      }

      float ssum = 0.f;
#pragma unroll
      for (int i = 0; i < 16; ++i) {
        float e = __expf(p[i] - m_run);
        p[i] = e;
        ssum += e;
      }
      ssum += __shfl_xor(ssum, 16);
      ssum += __shfl_xor(ssum, 32);
      l_run += ssum;

#pragma unroll
      for (int n = 0; n < 4; ++n) {
        ushort4 w;
        w.x = f2b(p[n * 4 + 0]); w.y = f2b(p[n * 4 + 1]);
        w.z = f2b(p[n * 4 + 2]); w.w = f2b(p[n * 4 + 3]);
        *(ushort4*)(void*)&Pl[wave][lr][n * 16 + g * 4] = w;
      }

#pragma unroll
      for (int half = 0; half < 2; ++half) {
        bf16x8_t pf = *(const bf16x8_t*)(const void*)&Pl[wave][lr][half * 32 + lk8];
#pragma unroll
        for (int c = 0; c < 8; ++c) {
          bf16x8_t vf = *(const bf16x8_t*)(const void*)&Vt[c * 16 + lr][half * 32 + lk8];
          oacc[c] = __builtin_amdgcn_mfma_f32_16x16x32_bf16(pf, vf, oacc[c], 0, 0, 0);
        }
      }
    }

    float linv[4];
#pragma unroll
    for (int r = 0; r < 4; ++r) linv[r] = 1.f / __shfl(l_run, g * 4 + r);
#pragma unroll
    for (int r = 0; r < 4; ++r) {
      int row = qrow + g * 4 + r;
#pragma unroll
      for (int c = 0; c < 8; ++c)
        O[(size_t)row * HID + (size_t)h * HD + c * 16 + lr] = f2b(oacc[c][r] * linv[r]);
    }
  }
}

// ---------------- host launch ----------------
extern "C" void kernel_launch(void* const* d_in, const int* in_sizes, int n_in,
                              void* d_out, int out_size, void* d_ws, size_t ws_size,
                              hipStream_t stream) {
  (void)in_sizes; (void)n_in; (void)out_size; (void)ws_size;
  const float* X  = (const float*)d_in[0];
  const float* Wq = (const float*)d_in[1];
  const float* Wk = (const float*)d_in[2];
  const float* Wv = (const float*)d_in[3];
  const float* Wo = (const float*)d_in[4];
  const int*  pos = (const int*)d_in[5];
  float* out = (float*)d_out;

  unsigned short* Xb  = (unsigned short*)d_ws;
  unsigned short* Wqb = Xb  + (size_t)S_LEN * HID;
  unsigned short* Wkb = Wqb + (size_t)HID * HID;    // contiguous with Wqb
  unsigned short* Wvb = Wkb + (size_t)KVW * HID;    // contiguous -> [6144 x 4096] B
  unsigned short* Wob = Wvb + (size_t)KVW * HID;
  unsigned short* Qb  = Wob + (size_t)HID * HID;
  unsigned short* Kb  = Qb  + (size_t)S_LEN * HID;
  unsigned short* VtB = Kb  + (size_t)S_LEN * KVW;  // V^T: [KVW][S_LEN]
  unsigned short* AOb = VtB + (size_t)S_LEN * KVW;

  auto cvt = [&](const float* s, unsigned short* d, size_t n) {
    int n4 = (int)(n / 4);
    int grid = (n4 + 255) / 256;
    if (grid > 4096) grid = 4096;
    cvt_kernel<<<grid, 256, 0, stream>>>(s, d, n4);
  };
  cvt(X,  Xb,  (size_t)S_LEN * HID);
  cvt(Wq, Wqb, (size_t)HID * HID);
  cvt(Wk, Wkb, (size_t)KVW * HID);
  cvt(Wv, Wvb, (size_t)KVW * HID);
  cvt(Wo, Wob, (size_t)HID * HID);

  // QKV projection: 256x192 tiles, grid 32x8 = 256 blocks (full chip)
  gemm8p_kernel<192, 2><<<dim3(QKVN / 192, S_LEN / 256), 512, 0, stream>>>(
      Xb, Wqb, Qb, Kb, VtB, QKVN, HID);

  rope_kernel<<<2048, 256, 0, stream>>>(Qb, Kb, pos);

  // folded-balance attention: 16 pair-blocks x 32 heads
  attn_kernel<<<dim3(16, NH), 256, 0, stream>>>(Qb, Kb, VtB, AOb);

  // output projection: 256x128 tiles, grid 32x8 = 256 blocks -> fp32
  gemm8p_kernel<128, 1><<<dim3(HID / 128, S_LEN / 256), 512, 0, stream>>>(
      AOb, Wob, out, nullptr, nullptr, HID, HID);
}

// Round 10
// 299.238 us; speedup vs baseline: 1.1178x; 1.0297x over previous
//
#include <hip/hip_runtime.h>
#include <hip/hip_bf16.h>
#include <cstdint>
#include <cstddef>

#define S_LEN 2048
#define HID   4096
#define HD    128
#define NH    32
#define NKV   8
#define KVW   (NKV * HD)        /* 1024 */
#define QKVN  (HID + 2 * KVW)   /* 6144 */

typedef __bf16 bf16x8_t __attribute__((ext_vector_type(8)));
typedef float  f32x4_t  __attribute__((ext_vector_type(4)));
typedef unsigned short u16x8_t __attribute__((ext_vector_type(8)));

__device__ __forceinline__ unsigned short f2b(float f) {
  unsigned u = __float_as_uint(f);
  u += 0x7FFFu + ((u >> 16) & 1u);
  return (unsigned short)(u >> 16);
}
__device__ __forceinline__ float b2f(unsigned short v) {
  return __uint_as_float(((unsigned)v) << 16);
}
__device__ __forceinline__ void gld_lds16(const void* g, void* l) {
  __builtin_amdgcn_global_load_lds(
      (const __attribute__((address_space(1))) void*)g,
      (__attribute__((address_space(3))) void*)l, 16, 0, 0);
}

// ---------------- fp32 -> bf16 conversion ----------------
__global__ void cvt_kernel(const float* __restrict__ src,
                           unsigned short* __restrict__ dst, int n4) {
  int i = blockIdx.x * blockDim.x + threadIdx.x;
  int stride = gridDim.x * blockDim.x;
  for (; i < n4; i += stride) {
    float4 v = reinterpret_cast<const float4*>(src)[i];
    ushort4 o;
    o.x = f2b(v.x); o.y = f2b(v.y); o.z = f2b(v.z); o.w = f2b(v.w);
    reinterpret_cast<ushort4*>(dst)[i] = o;
  }
}

// ---------------- RoPE (in-place on bf16 Q and K) ----------------
__global__ void rope_kernel(unsigned short* __restrict__ Q,
                            unsigned short* __restrict__ Kb,
                            const int* __restrict__ pos_ids) {
  const int total = S_LEN * (NH + NKV) * 64;
  int idx = blockIdx.x * blockDim.x + threadIdx.x;
  int stride = gridDim.x * blockDim.x;
  for (; idx < total; idx += stride) {
    int s   = idx / ((NH + NKV) * 64);
    int rem = idx % ((NH + NKV) * 64);
    int hp  = rem >> 6;
    int i   = rem & 63;
    unsigned short* ptr; int W, h;
    if (hp < NH) { ptr = Q;  W = HID; h = hp; }
    else         { ptr = Kb; W = KVW; h = hp - NH; }
    float pos = (float)pos_ids[s];
    float ang = pos * __expf(-(float)i * 0.14391156516f); // ln(10000)/64
    float sn, cs;
    sincosf(ang, &sn, &cs);
    size_t base = (size_t)s * W + (size_t)h * HD + i;
    float lo = b2f(ptr[base]);
    float hi = b2f(ptr[base + 64]);
    ptr[base]      = f2b(lo * cs - hi * sn);
    ptr[base + 64] = f2b(hi * cs + lo * sn);
  }
}

// ------------- 4-phase pipelined GEMM, 2 blocks/CU: C = A(MxK)*B(NxK)^T -------------
// BM=128 fixed, BK=64, 2 LDS buffers (tile parity). TILE_LDS = 16KB + BN*128;
// 2 buffers = 80KB (BN=192) / 64KB (BN=128) => TWO blocks resident per CU with
// independent barrier domains: one block's ds_read/barrier phase overlaps the
// other's MFMA phase (fixes the 1-block/CU phase serialization of r7-r9).
// 4 phases per 2 K-tiles: p1{B(E) all + A(E) m0,1 | stage A(tO)} p2{A(E) m2,3 |
// stage B(tE2), vmcnt(NFR)} p3{B(O) + A(O) m0,1 | stage A(tE2)} p4{A(O) m2,3 |
// stage B(tO2), vmcnt(NFR)}. Ledger: p2's vmcnt(NFR) drains A(tO)+B(tO) (tile O
// confirmed before p3); p4's drains B(tE2)+A(tE2) (tile E2 confirmed before next
// p1); last iteration p2 drains vmcnt(0), p4 skips. WAR: B region read-complete
// at p1-end barrier (B->regs in p1), A at p2/p4-end; every stage targets a
// region fenced by the preceding phase-end barrier. Swizzle byte^=(row&7)<<4
// both sides. Natural block order (XCD swizzle hurt L2 - r8).
// 512 thr = 8 waves (2M x 4N); per-wave out 64 x BN/4. Grid (N/BN, M/128).
// MODE 1: fp32 out. MODE 2: QKV split w/ V transposed.
template <int BN, int MODE>
__global__ __launch_bounds__(512, 4) void gemm4p_kernel(
    const unsigned short* __restrict__ A, const unsigned short* __restrict__ B,
    void* __restrict__ C0, void* __restrict__ C1, void* __restrict__ C2,
    int N, int K) {
  constexpr int NFR = BN / 64;           // n-frags per wave = B 8KB-units (3 or 2)
  constexpr int ABYTES = 128 * 128;      // 16 KB
  constexpr int TILE_LDS = ABYTES + BN * 128;
  __shared__ char ldsB[2 * TILE_LDS];

  const int tid  = threadIdx.x;
  const int lane = tid & 63;
  const int wid  = tid >> 6;
  const int wm = wid >> 2, wn = wid & 3;
  const int lr = lane & 15, g = lane >> 4;
  const int bm = blockIdx.y * 128;
  const int bn = blockIdx.x * BN;
  const int nk = K >> 6;
  const int ni = nk >> 1;
  const int xr = (lr & 7) << 4;

  // stage unit u of K-tile t into buf (t&1). u<2: A rows u*64..; u>=2: B rows.
  auto stage_u = [&](int t, int u) {
    if (t >= nk) return;
    const int riu = tid >> 3;
    const int cbs = ((tid & 7) << 4) ^ ((riu & 7) << 4);
    const char* src;
    if (u < 2)
      src = (const char*)A + ((size_t)(bm + u * 64 + riu) * K + t * 64) * 2 + cbs;
    else
      src = (const char*)B + ((size_t)(bn + (u - 2) * 64 + riu) * K + t * 64) * 2 + cbs;
    gld_lds16(src, ldsB + (t & 1) * TILE_LDS + u * 8192 + tid * 16);
  };

  auto rdA = [&](const char* bb, int m, int k) {
    const int row = wm * 64 + m * 16 + lr;
    return *(const bf16x8_t*)(bb + row * 128 + ((k * 64 + g * 16) ^ xr));
  };
  auto rdB = [&](const char* bb, int n, int k) {
    const int row = wn * (BN / 4) + n * 16 + lr;
    return *(const bf16x8_t*)(bb + ABYTES + row * 128 + ((k * 64 + g * 16) ^ xr));
  };

  // prologue: stage tiles 0,1 fully; drain; barrier
  for (int t = 0; t < 2; ++t)
    for (int u = 0; u < 2 + NFR; ++u) stage_u(t, u);
  asm volatile("s_waitcnt vmcnt(0)" ::: "memory");
  __builtin_amdgcn_sched_barrier(0);
  __builtin_amdgcn_s_barrier();

  f32x4_t acc[4][NFR];
#pragma unroll
  for (int m = 0; m < 4; ++m)
#pragma unroll
    for (int n = 0; n < NFR; ++n) acc[m][n] = f32x4_t{0.f, 0.f, 0.f, 0.f};

  bf16x8_t bfr[NFR][2], af[2][2];

#define MFMA_BLOCK(MB)                                                        \
  __builtin_amdgcn_s_setprio(1);                                              \
  _Pragma("unroll") for (int m = 0; m < 2; ++m)                               \
    _Pragma("unroll") for (int n = 0; n < NFR; ++n)                           \
      _Pragma("unroll") for (int k = 0; k < 2; ++k)                           \
        acc[(MB) + m][n] = __builtin_amdgcn_mfma_f32_16x16x32_bf16(           \
            af[m][k], bfr[n][k], acc[(MB) + m][n], 0, 0, 0);                  \
  __builtin_amdgcn_s_setprio(0);

#define GATE()                                                                \
  __builtin_amdgcn_s_barrier();                                               \
  asm volatile("s_waitcnt lgkmcnt(0)" ::: "memory");                          \
  __builtin_amdgcn_sched_barrier(0);

#define RD_A2(bb, m0)                                                         \
  _Pragma("unroll") for (int m = 0; m < 2; ++m)                               \
    _Pragma("unroll") for (int k = 0; k < 2; ++k)                             \
      af[m][k] = rdA(bb, (m0) + m, k);

#define RD_B(bb)                                                              \
  _Pragma("unroll") for (int n = 0; n < NFR; ++n)                             \
    _Pragma("unroll") for (int k = 0; k < 2; ++k)                             \
      bfr[n][k] = rdB(bb, n, k);

  for (int i = 0; i < ni; ++i) {
    const char* bE = ldsB;
    const char* bO = ldsB + TILE_LDS;
    const int tO = 2 * i + 1, tE2 = 2 * i + 2, tO2 = 2 * i + 3;
    const bool last = (i == ni - 1);

    // ---- p1: B(E) all + A(E) m0,1 | stage A(tO) ----
    RD_B(bE);
    RD_A2(bE, 0);
    if (i > 0) { stage_u(tO, 0); stage_u(tO, 1); }
    GATE(); MFMA_BLOCK(0);
    __builtin_amdgcn_s_barrier();

    // ---- p2: A(E) m2,3 | stage B(tE2); confirm tile O ----
    RD_A2(bE, 2);
#pragma unroll
    for (int u = 0; u < NFR; ++u) stage_u(tE2, 2 + u);
    GATE(); MFMA_BLOCK(2);
    if (last) { asm volatile("s_waitcnt vmcnt(0)" ::: "memory"); }
    else      { asm volatile("s_waitcnt vmcnt(%0)" :: "n"(NFR) : "memory"); }
    __builtin_amdgcn_sched_barrier(0);
    __builtin_amdgcn_s_barrier();

    // ---- p3: B(O) all + A(O) m0,1 | stage A(tE2) ----
    RD_B(bO);
    RD_A2(bO, 0);
    stage_u(tE2, 0); stage_u(tE2, 1);
    GATE(); MFMA_BLOCK(0);
    __builtin_amdgcn_s_barrier();

    // ---- p4: A(O) m2,3 | stage B(tO2); confirm tile E2 ----
    RD_A2(bO, 2);
#pragma unroll
    for (int u = 0; u < NFR; ++u) stage_u(tO2, 2 + u);
    GATE(); MFMA_BLOCK(2);
    if (!last) { asm volatile("s_waitcnt vmcnt(%0)" :: "n"(NFR) : "memory"); }
    __builtin_amdgcn_sched_barrier(0);
    __builtin_amdgcn_s_barrier();
  }
#undef MFMA_BLOCK
#undef GATE
#undef RD_A2
#undef RD_B

  // ---- epilogue ----
#pragma unroll
  for (int mf = 0; mf < 4; ++mf) {
    const int row0 = bm + wm * 64 + mf * 16 + g * 4;
#pragma unroll
    for (int nf = 0; nf < NFR; ++nf) {
      const int col = bn + wn * (BN / 4) + nf * 16 + lr;
      if constexpr (MODE == 1) {
#pragma unroll
        for (int r = 0; r < 4; ++r)
          ((float*)C0)[(size_t)(row0 + r) * N + col] = acc[mf][nf][r];
      } else {
        if (col < HID) {
#pragma unroll
          for (int r = 0; r < 4; ++r)
            ((unsigned short*)C0)[(size_t)(row0 + r) * HID + col] = f2b(acc[mf][nf][r]);
        } else if (col < HID + KVW) {
#pragma unroll
          for (int r = 0; r < 4; ++r)
            ((unsigned short*)C1)[(size_t)(row0 + r) * KVW + (col - HID)] = f2b(acc[mf][nf][r]);
        } else {
          const int c2 = col - HID - KVW;
          ushort4 w;
          w.x = f2b(acc[mf][nf][0]); w.y = f2b(acc[mf][nf][1]);
          w.z = f2b(acc[mf][nf][2]); w.w = f2b(acc[mf][nf][3]);
          *(ushort4*)(void*)&((unsigned short*)C2)[(size_t)c2 * S_LEN + row0] = w;
        }
      }
    }
  }
}

// ---------------- flash attention v3 (causal, GQA 4:1) ----------------
__global__ __launch_bounds__(256) void attn_kernel(
    const unsigned short* __restrict__ Q, const unsigned short* __restrict__ K,
    const unsigned short* __restrict__ VtG, unsigned short* __restrict__ O) {
  __shared__ unsigned short Kl[64][136];
  __shared__ unsigned short Vt[128][72];
  __shared__ unsigned short Pl[4][16][72];

  const int tid  = threadIdx.x;
  const int lane = tid & 63;
  const int wave = tid >> 6;
  const int h    = blockIdx.y;
  const int kvh  = h >> 2;
  const int pair = blockIdx.x;             // [0,16)
  const int lr   = lane & 15;
  const int g    = lane >> 4;
  const int lk8  = g * 8;
  const float scale = 0.08838834764831845f;  // 1/sqrt(128)
  const unsigned short* Vbase = VtG + (size_t)kvh * HD * S_LEN;

  const int ksr = tid >> 4, ksc = (tid & 15) * 8;
  const int vsr = tid >> 3, vsc = (tid & 7) * 8;

  for (int pass = 0; pass < 2; ++pass) {
    const int qb = pass == 0 ? (31 - pair) : pair;
    const int q0 = qb * 64;
    const int qrow = q0 + wave * 16;
    const int nkv = qb + 1;

    bf16x8_t qf[4];
    {
      const unsigned short* qp = Q + (size_t)(qrow + lr) * HID + (size_t)h * HD;
#pragma unroll
      for (int c = 0; c < 4; ++c)
        qf[c] = *(const bf16x8_t*)(const void*)(qp + c * 32 + lk8);
    }
    f32x4_t oacc[8];
#pragma unroll
    for (int c = 0; c < 8; ++c) oacc[c] = f32x4_t{0.f, 0.f, 0.f, 0.f};
    float m_run = -3e38f, l_run = 0.f;

    u16x8_t kr[4], vr[4];
#pragma unroll
    for (int i = 0; i < 4; ++i)
      kr[i] = *(const u16x8_t*)(const void*)(K + (size_t)(ksr + i * 16) * KVW +
                                             (size_t)kvh * HD + ksc);
#pragma unroll
    for (int i = 0; i < 4; ++i)
      vr[i] = *(const u16x8_t*)(const void*)(Vbase + (size_t)(vsr + i * 32) * S_LEN + vsc);

    for (int it = 0; it < nkv; ++it) {
      const int kv0 = it * 64;
      __builtin_amdgcn_s_barrier();
#pragma unroll
      for (int i = 0; i < 4; ++i)
        *(u16x8_t*)(void*)&Kl[ksr + i * 16][ksc] = kr[i];
#pragma unroll
      for (int i = 0; i < 4; ++i)
        *(u16x8_t*)(void*)&Vt[vsr + i * 32][vsc] = vr[i];
      if (it + 1 < nkv) {
        const int kn = kv0 + 64;
#pragma unroll
        for (int i = 0; i < 4; ++i)
          kr[i] = *(const u16x8_t*)(const void*)(K + (size_t)(kn + ksr + i * 16) * KVW +
                                                 (size_t)kvh * HD + ksc);
#pragma unroll
        for (int i = 0; i < 4; ++i)
          vr[i] = *(const u16x8_t*)(const void*)(Vbase + (size_t)(vsr + i * 32) * S_LEN +
                                                 kn + vsc);
      }
      asm volatile("s_waitcnt lgkmcnt(0)" ::: "memory");
      __builtin_amdgcn_sched_barrier(0);
      __builtin_amdgcn_s_barrier();

      f32x4_t sacc[4];
#pragma unroll
      for (int n = 0; n < 4; ++n) sacc[n] = f32x4_t{0.f, 0.f, 0.f, 0.f};
#pragma unroll
      for (int c = 0; c < 4; ++c) {
        bf16x8_t qc = qf[c];
#pragma unroll
        for (int n = 0; n < 4; ++n) {
          bf16x8_t kf = *(const bf16x8_t*)(const void*)&Kl[n * 16 + lr][c * 32 + lk8];
          sacc[n] = __builtin_amdgcn_mfma_f32_16x16x32_bf16(kf, qc, sacc[n], 0, 0, 0);
        }
      }

      const int qg = qrow + lr;
      const bool diag = (it == nkv - 1);
      float p[16];
      float mloc = -3e38f;
#pragma unroll
      for (int n = 0; n < 4; ++n)
#pragma unroll
        for (int r = 0; r < 4; ++r) {
          float x = sacc[n][r] * scale;
          if (diag) {
            int kg = kv0 + n * 16 + g * 4 + r;
            if (kg > qg) x = -3e38f;
          }
          p[n * 4 + r] = x;
          mloc = fmaxf(mloc, x);
        }
      mloc = fmaxf(mloc, __shfl_xor(mloc, 16));
      mloc = fmaxf(mloc, __shfl_xor(mloc, 32));

      if (__any(mloc > m_run + 8.f)) {
        float m_new = fmaxf(m_run, mloc);
        float alpha = __expf(m_run - m_new);
        float a4[4];
#pragma unroll
        for (int r = 0; r < 4; ++r) a4[r] = __shfl(alpha, g * 4 + r);
#pragma unroll
        for (int c = 0; c < 8; ++c)
#pragma unroll
          for (int r = 0; r < 4; ++r) oacc[c][r] *= a4[r];
        l_run *= alpha;
        m_run = m_new;
      }

      float ssum = 0.f;
#pragma unroll
      for (int i = 0; i < 16; ++i) {
        float e = __expf(p[i] - m_run);
        p[i] = e;
        ssum += e;
      }
      ssum += __shfl_xor(ssum, 16);
      ssum += __shfl_xor(ssum, 32);
      l_run += ssum;

#pragma unroll
      for (int n = 0; n < 4; ++n) {
        ushort4 w;
        w.x = f2b(p[n * 4 + 0]); w.y = f2b(p[n * 4 + 1]);
        w.z = f2b(p[n * 4 + 2]); w.w = f2b(p[n * 4 + 3]);
        *(ushort4*)(void*)&Pl[wave][lr][n * 16 + g * 4] = w;
      }

#pragma unroll
      for (int half = 0; half < 2; ++half) {
        bf16x8_t pf = *(const bf16x8_t*)(const void*)&Pl[wave][lr][half * 32 + lk8];
#pragma unroll
        for (int c = 0; c < 8; ++c) {
          bf16x8_t vf = *(const bf16x8_t*)(const void*)&Vt[c * 16 + lr][half * 32 + lk8];
          oacc[c] = __builtin_amdgcn_mfma_f32_16x16x32_bf16(pf, vf, oacc[c], 0, 0, 0);
        }
      }
    }

    float linv[4];
#pragma unroll
    for (int r = 0; r < 4; ++r) linv[r] = 1.f / __shfl(l_run, g * 4 + r);
#pragma unroll
    for (int r = 0; r < 4; ++r) {
      int row = qrow + g * 4 + r;
#pragma unroll
      for (int c = 0; c < 8; ++c)
        O[(size_t)row * HID + (size_t)h * HD + c * 16 + lr] = f2b(oacc[c][r] * linv[r]);
    }
  }
}

// ---------------- host launch ----------------
extern "C" void kernel_launch(void* const* d_in, const int* in_sizes, int n_in,
                              void* d_out, int out_size, void* d_ws, size_t ws_size,
                              hipStream_t stream) {
  (void)in_sizes; (void)n_in; (void)out_size; (void)ws_size;
  const float* X  = (const float*)d_in[0];
  const float* Wq = (const float*)d_in[1];
  const float* Wk = (const float*)d_in[2];
  const float* Wv = (const float*)d_in[3];
  const float* Wo = (const float*)d_in[4];
  const int*  pos = (const int*)d_in[5];
  float* out = (float*)d_out;

  unsigned short* Xb  = (unsigned short*)d_ws;
  unsigned short* Wqb = Xb  + (size_t)S_LEN * HID;
  unsigned short* Wkb = Wqb + (size_t)HID * HID;    // contiguous with Wqb
  unsigned short* Wvb = Wkb + (size_t)KVW * HID;    // contiguous -> [6144 x 4096] B
  unsigned short* Wob = Wvb + (size_t)KVW * HID;
  unsigned short* Qb  = Wob + (size_t)HID * HID;
  unsigned short* Kb  = Qb  + (size_t)S_LEN * HID;
  unsigned short* VtB = Kb  + (size_t)S_LEN * KVW;  // V^T: [KVW][S_LEN]
  unsigned short* AOb = VtB + (size_t)S_LEN * KVW;

  auto cvt = [&](const float* s, unsigned short* d, size_t n) {
    int n4 = (int)(n / 4);
    int grid = (n4 + 255) / 256;
    if (grid > 4096) grid = 4096;
    cvt_kernel<<<grid, 256, 0, stream>>>(s, d, n4);
  };
  cvt(X,  Xb,  (size_t)S_LEN * HID);
  cvt(Wq, Wqb, (size_t)HID * HID);
  cvt(Wk, Wkb, (size_t)KVW * HID);
  cvt(Wv, Wvb, (size_t)KVW * HID);
  cvt(Wo, Wob, (size_t)HID * HID);

  // QKV projection: 128x192 tiles, grid 32x16 = 512 blocks (2 per CU)
  gemm4p_kernel<192, 2><<<dim3(QKVN / 192, S_LEN / 128), 512, 0, stream>>>(
      Xb, Wqb, Qb, Kb, VtB, QKVN, HID);

  rope_kernel<<<2048, 256, 0, stream>>>(Qb, Kb, pos);

  // folded-balance attention: 16 pair-blocks x 32 heads
  attn_kernel<<<dim3(16, NH), 256, 0, stream>>>(Qb, Kb, VtB, AOb);

  // output projection: 128x128 tiles, grid 32x16 = 512 blocks (2 per CU) -> fp32
  gemm4p_kernel<128, 1><<<dim3(HID / 128, S_LEN / 128), 512, 0, stream>>>(
      AOb, Wob, out, nullptr, nullptr, HID, HID);
}